// Round 12
// baseline (156.029 us; speedup 1.0000x reference)
//
#include <hip/hip_runtime.h>
#include <math.h>

#define NOISE 1e-12f
#define WSZ 1064    // floats per staging buffer: THc(200) | F(64) | G1n0c(200) | G1n1c(200) | G2n0c(200) | G2n1c(200)
#define WSZ4 266

typedef float f32x2 __attribute__((ext_vector_type(2)));

__device__ __forceinline__ f32x2 mk2(float x, float y){ f32x2 r; r.x = x; r.y = y; return r; }

// packed complex multiply: returns a (x) b, 2 VOP3P instructions
__device__ __forceinline__ f32x2 cmul_pk(f32x2 a, f32x2 b) {
    f32x2 w;
    asm("v_pk_mul_f32 %0, %1, %2 op_sel:[0,0] op_sel_hi:[0,1]\n\t"
        "v_pk_fma_f32 %0, %1, %2, %0 op_sel:[1,1,0] op_sel_hi:[1,0,1] neg_lo:[0,1,0]"
        : "=&v"(w) : "v"(a), "v"(b));
    return w;
}
// packed complex FMA: p += a (x) w, 2 VOP3P instructions
__device__ __forceinline__ void cfma_pk(f32x2& p, f32x2 a, f32x2 w) {
    asm("v_pk_fma_f32 %0, %1, %2, %0 op_sel:[0,0,0] op_sel_hi:[0,1,1]\n\t"
        "v_pk_fma_f32 %0, %1, %2, %0 op_sel:[1,1,0] op_sel_hi:[1,0,1] neg_lo:[0,1,0]"
        : "+v"(p) : "v"(a), "v"(w));
}

__device__ __forceinline__ float2 cmul(float2 a, float2 b) {
    return make_float2(a.x*b.x - a.y*b.y, a.x*b.y + a.y*b.x);
}
__device__ __forceinline__ float2 cconjmul(float2 a, float2 b) {
    return make_float2(a.x*b.x + a.y*b.y, a.x*b.y - a.y*b.x);
}
__device__ __forceinline__ float2 cmulconj(float2 a, float2 b) {
    return make_float2(a.x*b.x + a.y*b.y, a.y*b.x - a.x*b.y);
}
__device__ __forceinline__ float2 cadd(float2 a, float2 b){ return make_float2(a.x+b.x, a.y+b.y); }
__device__ __forceinline__ float2 csub(float2 a, float2 b){ return make_float2(a.x-b.x, a.y-b.y); }
__device__ __forceinline__ float2 cscale(float s, float2 a){ return make_float2(s*a.x, s*a.y); }

// one wave per batch element iteration; 4 waves/block; 4 iterations -> 16 b per block
__global__ __launch_bounds__(256) void rate_kernel(
    const float* __restrict__ t1,
    const float* __restrict__ G1r, const float* __restrict__ G1i,
    const float* __restrict__ G2r, const float* __restrict__ G2i,
    const float* __restrict__ Ur,  const float* __restrict__ Ui,
    float* __restrict__ partial)
{
    __shared__ float4 lds4[4 * 2 * WSZ4];  // per-wave double-buffered staging
    __shared__ float2 ent[4][4][16];       // [wave][it][entry]
    __shared__ float wsum[4];
    const int wave = threadIdx.x >> 6;
    const int lane = threadIdx.x & 63;
    const int t  = lane & 7;     // output column of phi
    const int k0 = lane >> 3;    // k-block id: lane handles k = 4*k0 + 32*j + c
    const int e8 = k0;
    const int nn = (e8 >> 1) & 1;
    const int rr = e8 & 1;
    float* Wbuf = (float*)(lds4 + wave * 2 * WSZ4);

    // ---- reg-held staging: load early into regs, write interleaved to the
    // OTHER dbuf half late (no reader conflict). 7 float4 = 28 VGPR held. ----
    float4 s_tr, s_ti, s_f, s_ar, s_ai, s_br, s_bi;
    #define STAGE_LOAD(bb) {                                                  \
        const float* tb_ = t1 + (long)(bb) * 264;                             \
        if (lane < 25) { s_tr = ((const float4*)tb_)[lane];                   \
                         s_ti = ((const float4*)(tb_ + 100))[lane]; }         \
        if (lane < 16)   s_f  = ((const float4*)(tb_ + 200))[lane];           \
        if (lane < 50) { s_ar = ((const float4*)(G1r + (long)(bb)*200))[lane];\
                         s_ai = ((const float4*)(G1i + (long)(bb)*200))[lane];\
                         s_br = ((const float4*)(G2r + (long)(bb)*200))[lane];\
                         s_bi = ((const float4*)(G2i + (long)(bb)*200))[lane];}\
    }
    // LDS layout (floats): THc[0..199] (re,im)x100 | F[200..263] raw |
    //   G1c[264..663] rows n0,n1 interleaved | G2c[664..1063]
    #define STAGE_WRITE(dst) {                                                \
        if (lane < 25) { float4* d = (float4*)(dst) + 2*lane;                 \
            d[0] = make_float4(s_tr.x, s_ti.x, s_tr.y, s_ti.y);               \
            d[1] = make_float4(s_tr.z, s_ti.z, s_tr.w, s_ti.w); }             \
        if (lane < 16) ((float4*)((dst) + 200))[lane] = s_f;                  \
        if (lane < 50) { float4* d = (float4*)((dst) + 264) + 2*lane;         \
            d[0] = make_float4(s_ar.x, s_ai.x, s_ar.y, s_ai.y);               \
            d[1] = make_float4(s_ar.z, s_ai.z, s_ar.w, s_ai.w);               \
            d = (float4*)((dst) + 664) + 2*lane;                              \
            d[0] = make_float4(s_br.x, s_bi.x, s_br.y, s_bi.y);               \
            d[1] = make_float4(s_br.z, s_bi.z, s_br.w, s_bi.w); }             \
    }

    const long bbase = (long)blockIdx.x * 16 + (long)wave * 4;
    STAGE_LOAD(bbase);
    STAGE_WRITE(Wbuf);   // prologue fill of buffer 0

    const float* urb = Ur + bbase * 800;
    const float* uib = Ui + bbase * 800;
    const int uoff = 32 * k0 + t;
    #define LDU2(idx) mk2(urb[(idx)], uib[(idx)])

    // initial U prefetch for it 0, j=0
    f32x2 u0 = LDU2(uoff), u1 = LDU2(uoff+8), u2 = LDU2(uoff+16), u3 = LDU2(uoff+24);

    // one j-group: 10 ds_read_b128 + 4 k's of packed complex math (40 VOP3P)
    #define JGROUP_PK(f0, U0, U1, U2, U3) {                                   \
        float4 t01 = F4[(f0)],      t23 = F4[(f0)+1];                         \
        float4 a01 = F4[66+(f0)],   a23 = F4[67+(f0)];                        \
        float4 c01 = F4[116+(f0)],  c23 = F4[117+(f0)];                       \
        float4 d01 = F4[166+(f0)],  d23 = F4[167+(f0)];                       \
        float4 e01 = F4[216+(f0)],  e23 = F4[217+(f0)];                       \
        { f32x2 Wk = cmul_pk(mk2(t01.x,t01.y), U0);                           \
          cfma_pk(p10, mk2(a01.x,a01.y), Wk); cfma_pk(p11, mk2(c01.x,c01.y), Wk); \
          cfma_pk(p20, mk2(d01.x,d01.y), Wk); cfma_pk(p21, mk2(e01.x,e01.y), Wk); } \
        { f32x2 Wk = cmul_pk(mk2(t01.z,t01.w), U1);                           \
          cfma_pk(p10, mk2(a01.z,a01.w), Wk); cfma_pk(p11, mk2(c01.z,c01.w), Wk); \
          cfma_pk(p20, mk2(d01.z,d01.w), Wk); cfma_pk(p21, mk2(e01.z,e01.w), Wk); } \
        { f32x2 Wk = cmul_pk(mk2(t23.x,t23.y), U2);                           \
          cfma_pk(p10, mk2(a23.x,a23.y), Wk); cfma_pk(p11, mk2(c23.x,c23.y), Wk); \
          cfma_pk(p20, mk2(d23.x,d23.y), Wk); cfma_pk(p21, mk2(e23.x,e23.y), Wk); } \
        { f32x2 Wk = cmul_pk(mk2(t23.z,t23.w), U3);                           \
          cfma_pk(p10, mk2(a23.z,a23.w), Wk); cfma_pk(p11, mk2(c23.z,c23.w), Wk); \
          cfma_pk(p20, mk2(d23.z,d23.w), Wk); cfma_pk(p21, mk2(e23.z,e23.w), Wk); } }

    for (int it = 0; it < 4; ++it) {
        float* W = Wbuf + (it & 1) * WSZ;
        const float4* F4 = (const float4*)W;

        // issue next it's staging loads NOW; pin them here (no sinking), they
        // fly under this it's whole compute phase.
        if (it < 3) {
            STAGE_LOAD(bbase + it + 1);
            __builtin_amdgcn_sched_barrier(0);
        }

        // phi accumulators (packed re,im): p10=phi1 n0, p11=phi1 n1, p20/p21=phi2
        f32x2 p10 = mk2(0.f,0.f), p11 = mk2(0.f,0.f);
        f32x2 p20 = mk2(0.f,0.f), p21 = mk2(0.f,0.f);

        #pragma unroll 1   // rolled: keep VGPR bounded; prefetch provides ILP
        for (int j = 0; j < 3; ++j) {
            f32x2 n0, n1, n2, n3;
            if (j < 2) {
                const int nb = uoff + 256 * (j + 1);
                n0 = LDU2(nb); n1 = LDU2(nb+8); n2 = LDU2(nb+16); n3 = LDU2(nb+24);
            } else {
                // tail strips k=96..99: idx <= 799, in-bounds for all lanes
                n0 = LDU2(768+t); n1 = LDU2(776+t); n2 = LDU2(784+t); n3 = LDU2(792+t);
            }
            JGROUP_PK(2*k0 + 16*j, u0, u1, u2, u3);
            u0 = n0; u1 = n1; u2 = n2; u3 = n3;
        }
        // tail: k = 96..99, only k0==0 lanes contribute (f0 = 96/2 = 48)
        if (k0 == 0) {
            JGROUP_PK(48, u0, u1, u2, u3);
        }

        // cross-it U prefetch: next it's j=0 strips; shuffle phase covers latency
        if (it < 3) {
            urb += 800; uib += 800;
            u0 = LDU2(uoff); u1 = LDU2(uoff+8); u2 = LDU2(uoff+16); u3 = LDU2(uoff+24);
        }

        // reduce over the 8 k-blocks (lane bits 3..5)
        float p[8] = {p10.x, p10.y, p11.x, p11.y, p20.x, p20.y, p21.x, p21.y};
        #pragma unroll
        for (int q = 0; q < 8; ++q) {
            p[q] += __shfl_xor(p[q], 8);
            p[q] += __shfl_xor(p[q], 32);
        }
        float4 ph;
        {
            float k0r = nn ? p[2] : p[0], s0r = nn ? p[0] : p[2];
            float k0i = nn ? p[3] : p[1], s0i = nn ? p[1] : p[3];
            float k1r = nn ? p[6] : p[4], s1r = nn ? p[4] : p[6];
            float k1i = nn ? p[7] : p[5], s1i = nn ? p[5] : p[7];
            ph.x = k0r + __shfl_xor(s0r, 16);
            ph.y = k0i + __shfl_xor(s0i, 16);
            ph.z = k1r + __shfl_xor(s1r, 16);
            ph.w = k1i + __shfl_xor(s1i, 16);
        }

        // ---- F norms ----  (F raw at W[200..263])
        float s1, s2;
        {
            int idx = lane & 15;
            int sel = (lane >> 4) & 1;
            float fr = W[200 + sel*32 + idx];
            float fi = W[216 + sel*32 + idx];
            float m = fr*fr + fi*fi;
            #pragma unroll
            for (int s = 1; s < 16; s <<= 1) m += __shfl_xor(m, s);
            float other = __shfl_xor(m, 16);
            float nrm1 = sel ? other : m;
            float nrm2 = sel ? m : other;
            s1 = sqrtf(2.0f / nrm1);
            s2 = sqrtf(2.0f / nrm2);
        }

        // ---- A/C entries: ent[it][0..7] = {A,C} for R1; [8..15] for R2 ----
        {
            int jf = t*2 + rr;
            float2 f1 = make_float2(W[200 + jf], W[216 + jf]);
            float2 f2 = make_float2(W[232 + jf], W[248 + jf]);
            float2 phi1n = make_float2(ph.x, ph.y);
            float2 phi2n = make_float2(ph.z, ph.w);
            bool lo = (e8 < 4);
            float2 E0 = cmul(phi1n, lo ? f1 : f2);
            float2 E1 = cmul(phi2n, lo ? f2 : f1);
            #pragma unroll
            for (int s = 1; s < 8; s <<= 1) {
                E0.x += __shfl_xor(E0.x, s); E0.y += __shfl_xor(E0.y, s);
                E1.x += __shfl_xor(E1.x, s); E1.y += __shfl_xor(E1.y, s);
            }
            if (t == 0) {
                ent[wave][it][e8]     = cscale(lo ? s1 : s2, E0);
                ent[wave][it][e8 + 8] = cscale(lo ? s2 : s1, E1);
            }
        }

        // write next it's staged data to the other dbuf half (readers done by
        // construction; same-wave DS ops retire in order before next it's reads)
        if (it < 3) {
            __builtin_amdgcn_sched_barrier(0);
            STAGE_WRITE(Wbuf + ((it + 1) & 1) * WSZ);
        }
    }
    #undef STAGE_LOAD
    #undef STAGE_WRITE
    #undef LDU2
    #undef JGROUP_PK
    asm volatile("s_waitcnt lgkmcnt(0)" ::: "memory");
    __builtin_amdgcn_wave_barrier();

    // ---- batched 2x2 complex rate: lanes 0..7 -> (it = lane>>1, R1/R2 = lane&1) ----
    float negR = 0.0f;
    if (lane < 8) {
        const float2* e = &ent[wave][lane >> 1][(lane & 1) * 8];
        float2 A00=e[0], A01=e[1], A10=e[2], A11=e[3];
        float2 C00=e[4], C01=e[5], C10=e[6], C11=e[7];
        float mu00 = C00.x*C00.x + C00.y*C00.y + C01.x*C01.x + C01.y*C01.y + NOISE;
        float mu11 = C10.x*C10.x + C10.y*C10.y + C11.x*C11.x + C11.y*C11.y + NOISE;
        float2 mu01 = cadd(cmulconj(C00, C10), cmulconj(C01, C11));
        mu01.x += NOISE;
        float det = mu00*mu11 - (mu01.x*mu01.x + mu01.y*mu01.y);
        float inv = 1.0f / det;
        float2 mu01c = make_float2(mu01.x, -mu01.y);
        float2 X00 = cscale(inv, csub(cscale(mu11, A00), cmul(mu01,  A10)));
        float2 X01 = cscale(inv, csub(cscale(mu11, A01), cmul(mu01,  A11)));
        float2 X10 = cscale(inv, csub(cscale(mu00, A10), cmul(mu01c, A00)));
        float2 X11 = cscale(inv, csub(cscale(mu00, A11), cmul(mu01c, A01)));
        float2 I00 = cadd(cconjmul(A00, X00), cconjmul(A10, X10));
        float2 I01 = cadd(cconjmul(A00, X01), cconjmul(A10, X11));
        float2 I10 = cadd(cconjmul(A01, X00), cconjmul(A11, X10));
        float2 I11 = cadd(cconjmul(A01, X01), cconjmul(A11, X11));
        I00.x += 1.0f; I01.x += 1.0f; I10.x += 1.0f; I11.x += 1.0f;
        float2 dT = csub(cmul(I00, I11), cmul(I01, I10));
        negR = -0.5f * logf(dT.x*dT.x + dT.y*dT.y);  // -Re(log z) = -ln|z|
    }
    // pairwise max over (R1,R2), then sum the 4 batch elements
    float m = fmaxf(negR, __shfl_xor(negR, 1));
    m += __shfl_xor(m, 2);
    m += __shfl_xor(m, 4);
    if (lane == 0) wsum[wave] = m;

    __syncthreads();
    if (threadIdx.x == 0)
        partial[blockIdx.x] = (wsum[0] + wsum[1]) + (wsum[2] + wsum[3]);
}

__global__ __launch_bounds__(256) void reduce_kernel(
    const float* __restrict__ partial, int n, float invB, float* __restrict__ out)
{
    __shared__ float sd[256];
    float s = 0.0f;
    for (int i = threadIdx.x; i < n; i += 256) s += partial[i];
    sd[threadIdx.x] = s;
    __syncthreads();
    for (int o = 128; o > 0; o >>= 1) {
        if ((int)threadIdx.x < o) sd[threadIdx.x] += sd[threadIdx.x + o];
        __syncthreads();
    }
    if (threadIdx.x == 0) out[0] = sd[0] * invB;
}

extern "C" void kernel_launch(void* const* d_in, const int* in_sizes, int n_in,
                              void* d_out, int out_size, void* d_ws, size_t ws_size,
                              hipStream_t stream) {
    const float* t1  = (const float*)d_in[0];
    const float* G1r = (const float*)d_in[1];
    const float* G1i = (const float*)d_in[2];
    const float* G2r = (const float*)d_in[3];
    const float* G2i = (const float*)d_in[4];
    const float* Ur  = (const float*)d_in[5];
    const float* Ui  = (const float*)d_in[6];

    const int B = in_sizes[0] / 264;        // 65536
    const int nblocks = B / 16;             // 16 batch elements per block
    float* partial = (float*)d_ws;          // nblocks floats

    rate_kernel<<<nblocks, 256, 0, stream>>>(t1, G1r, G1i, G2r, G2i, Ur, Ui, partial);
    reduce_kernel<<<1, 256, 0, stream>>>(partial, nblocks, 1.0f / (float)B, (float*)d_out);
}

// Round 13
// 137.799 us; speedup vs baseline: 1.1323x; 1.1323x over previous
//
#include <hip/hip_runtime.h>
#include <math.h>

#define NOISE 1e-12f
#define WSZ 1064    // floats per staging buffer: THc(200) | F(64) | G1c(400) | G2c(400)
#define WSZ4 266

typedef float f32x2 __attribute__((ext_vector_type(2)));

__device__ __forceinline__ f32x2 mk2(float x, float y){ f32x2 r; r.x = x; r.y = y; return r; }

// packed complex multiply: returns a (x) b, 2 VOP3P instructions
__device__ __forceinline__ f32x2 cmul_pk(f32x2 a, f32x2 b) {
    f32x2 w;
    asm("v_pk_mul_f32 %0, %1, %2 op_sel:[0,0] op_sel_hi:[0,1]\n\t"
        "v_pk_fma_f32 %0, %1, %2, %0 op_sel:[1,1,0] op_sel_hi:[1,0,1] neg_lo:[0,1,0]"
        : "=&v"(w) : "v"(a), "v"(b));
    return w;
}
// packed complex FMA: p += a (x) w, 2 VOP3P instructions
__device__ __forceinline__ void cfma_pk(f32x2& p, f32x2 a, f32x2 w) {
    asm("v_pk_fma_f32 %0, %1, %2, %0 op_sel:[0,0,0] op_sel_hi:[0,1,1]\n\t"
        "v_pk_fma_f32 %0, %1, %2, %0 op_sel:[1,1,0] op_sel_hi:[1,0,1] neg_lo:[0,1,0]"
        : "+v"(p) : "v"(a), "v"(w));
}

__device__ __forceinline__ float2 cmul(float2 a, float2 b) {
    return make_float2(a.x*b.x - a.y*b.y, a.x*b.y + a.y*b.x);
}
__device__ __forceinline__ float2 cconjmul(float2 a, float2 b) {
    return make_float2(a.x*b.x + a.y*b.y, a.x*b.y - a.y*b.x);
}
__device__ __forceinline__ float2 cmulconj(float2 a, float2 b) {
    return make_float2(a.x*b.x + a.y*b.y, a.y*b.x - a.x*b.y);
}
__device__ __forceinline__ float2 cadd(float2 a, float2 b){ return make_float2(a.x+b.x, a.y+b.y); }
__device__ __forceinline__ float2 csub(float2 a, float2 b){ return make_float2(a.x-b.x, a.y-b.y); }
__device__ __forceinline__ float2 cscale(float s, float2 a){ return make_float2(s*a.x, s*a.y); }

// async global->LDS, 4 B per lane: lane l writes dst+4*l from per-lane src.
// Even/odd lane split performs the (re,im) interleave in the DMA engine.
typedef const void __attribute__((address_space(1)))* gas_t;
typedef void __attribute__((address_space(3)))* las_t;
__device__ __forceinline__ void gll4(const float* g, float* l) {
    __builtin_amdgcn_global_load_lds((gas_t)g, (las_t)l, 4, 0, 0);
}

// one wave per batch element iteration; 4 waves/block; 4 iterations -> 16 b per block
__global__ __launch_bounds__(256) void rate_kernel(
    const float* __restrict__ t1,
    const float* __restrict__ G1r, const float* __restrict__ G1i,
    const float* __restrict__ G2r, const float* __restrict__ G2i,
    const float* __restrict__ Ur,  const float* __restrict__ Ui,
    float* __restrict__ partial)
{
    __shared__ float4 lds4[4 * 2 * WSZ4];  // per-wave double-buffered staging
    __shared__ float2 ent[4][4][16];       // [wave][it][entry]
    __shared__ float wsum[4];
    const int wave = threadIdx.x >> 6;
    const int lane = threadIdx.x & 63;
    const int t  = lane & 7;     // output column of phi
    const int k0 = lane >> 3;    // k-block id: lane handles k = 4*k0 + 32*j + c
    const int e8 = k0;
    const int nn = (e8 >> 1) & 1;
    const int rr = e8 & 1;
    float* Wbuf = (float*)(lds4 + wave * 2 * WSZ4);

    const int half  = lane & 1;     // 0 -> re stream, 1 -> im stream
    const int qh    = lane >> 1;    // complex index within a 32-pair chunk

    // LDS layout (floats): THc[0..199]=(θr,θi)x100 | F[200..263] raw tb[200..263] |
    //   G1c[264..663]=(g1r,g1i)x200 | G2c[664..1063]
    // 19 vmcnt-counted gll4 issues; no VGPRs held, no DS writes.
    #define STAGE(dst, bb) {                                                   \
        const float* tb_ = t1 + (long)(bb) * 264;                              \
        const float* ts  = tb_ + (half ? 100 : 0) + qh;                        \
        gll4(ts,       (dst));        gll4(ts + 32,  (dst) + 64);              \
        gll4(ts + 64,  (dst) + 128);                                           \
        if (lane < 8) gll4(ts + 96, (dst) + 192);                              \
        gll4(tb_ + 200 + lane, (dst) + 200);                                   \
        const float* g1 = (half ? G1i : G1r) + (long)(bb) * 200 + qh;          \
        const float* g2 = (half ? G2i : G2r) + (long)(bb) * 200 + qh;          \
        gll4(g1,        (dst)+264);   gll4(g1+32,  (dst)+328);                 \
        gll4(g1+64,     (dst)+392);   gll4(g1+96,  (dst)+456);                 \
        gll4(g1+128,    (dst)+520);   gll4(g1+160, (dst)+584);                 \
        if (lane < 16) gll4(g1+192, (dst)+648);                                \
        gll4(g2,        (dst)+664);   gll4(g2+32,  (dst)+728);                 \
        gll4(g2+64,     (dst)+792);   gll4(g2+96,  (dst)+856);                 \
        gll4(g2+128,    (dst)+920);   gll4(g2+160, (dst)+984);                 \
        if (lane < 16) gll4(g2+192, (dst)+1048);                               \
    }

    const long bbase = (long)blockIdx.x * 16 + (long)wave * 4;
    STAGE(Wbuf, bbase);   // prologue: buffer 0 for it 0

    const float* urb = Ur + bbase * 800;
    const float* uib = Ui + bbase * 800;
    const int uoff = 32 * k0 + t;
    #define LDU2(idx) mk2(urb[(idx)], uib[(idx)])

    // initial U prefetch for it 0, j=0
    f32x2 u0 = LDU2(uoff), u1 = LDU2(uoff+8), u2 = LDU2(uoff+16), u3 = LDU2(uoff+24);

    // one j-group: 10 ds_read_b128 + 4 k's of packed complex math (40 VOP3P)
    #define JGROUP_PK(f0, U0, U1, U2, U3) {                                   \
        float4 t01 = F4[(f0)],      t23 = F4[(f0)+1];                         \
        float4 a01 = F4[66+(f0)],   a23 = F4[67+(f0)];                        \
        float4 c01 = F4[116+(f0)],  c23 = F4[117+(f0)];                       \
        float4 d01 = F4[166+(f0)],  d23 = F4[167+(f0)];                       \
        float4 e01 = F4[216+(f0)],  e23 = F4[217+(f0)];                       \
        { f32x2 Wk = cmul_pk(mk2(t01.x,t01.y), U0);                           \
          cfma_pk(p10, mk2(a01.x,a01.y), Wk); cfma_pk(p11, mk2(c01.x,c01.y), Wk); \
          cfma_pk(p20, mk2(d01.x,d01.y), Wk); cfma_pk(p21, mk2(e01.x,e01.y), Wk); } \
        { f32x2 Wk = cmul_pk(mk2(t01.z,t01.w), U1);                           \
          cfma_pk(p10, mk2(a01.z,a01.w), Wk); cfma_pk(p11, mk2(c01.z,c01.w), Wk); \
          cfma_pk(p20, mk2(d01.z,d01.w), Wk); cfma_pk(p21, mk2(e01.z,e01.w), Wk); } \
        { f32x2 Wk = cmul_pk(mk2(t23.x,t23.y), U2);                           \
          cfma_pk(p10, mk2(a23.x,a23.y), Wk); cfma_pk(p11, mk2(c23.x,c23.y), Wk); \
          cfma_pk(p20, mk2(d23.x,d23.y), Wk); cfma_pk(p21, mk2(e23.x,e23.y), Wk); } \
        { f32x2 Wk = cmul_pk(mk2(t23.z,t23.w), U3);                           \
          cfma_pk(p10, mk2(a23.z,a23.w), Wk); cfma_pk(p11, mk2(c23.z,c23.w), Wk); \
          cfma_pk(p20, mk2(d23.z,d23.w), Wk); cfma_pk(p21, mk2(e23.z,e23.w), Wk); } }

    for (int it = 0; it < 4; ++it) {
        float* W = Wbuf + (it & 1) * WSZ;
        const float4* F4 = (const float4*)W;

        // issue next it's staging first (flies under this it's compute).
        // Outstanding at the wait: [8 prefetched U][19 new gll4] = 27 ->
        // vmcnt(27) drains exactly the CURRENT buffer's staging. it3 needs no
        // wait: its buffer was staged in it2, and it2's U loads (issued after,
        // consumed with compiler waits) imply in-order retirement.
        if (it < 3) {
            STAGE(Wbuf + ((it + 1) & 1) * WSZ, bbase + it + 1);
            asm volatile("s_waitcnt vmcnt(27)" ::: "memory");
        }
        __builtin_amdgcn_sched_barrier(0);

        // phi accumulators (packed re,im): p10=phi1 n0, p11=phi1 n1, p20/p21=phi2
        f32x2 p10 = mk2(0.f,0.f), p11 = mk2(0.f,0.f);
        f32x2 p20 = mk2(0.f,0.f), p21 = mk2(0.f,0.f);

        #pragma unroll 1   // rolled: keep VGPR bounded; prefetch provides ILP
        for (int j = 0; j < 3; ++j) {
            f32x2 n0, n1, n2, n3;
            if (j < 2) {
                const int nb = uoff + 256 * (j + 1);
                n0 = LDU2(nb); n1 = LDU2(nb+8); n2 = LDU2(nb+16); n3 = LDU2(nb+24);
            } else {
                // tail strips k=96..99: idx <= 799, in-bounds for all lanes
                n0 = LDU2(768+t); n1 = LDU2(776+t); n2 = LDU2(784+t); n3 = LDU2(792+t);
            }
            JGROUP_PK(2*k0 + 16*j, u0, u1, u2, u3);
            u0 = n0; u1 = n1; u2 = n2; u3 = n3;
        }
        // tail: k = 96..99, only k0==0 lanes contribute (f0 = 2*96/4 = 48)
        if (k0 == 0) {
            JGROUP_PK(48, u0, u1, u2, u3);
        }

        // cross-it U prefetch: next it's j=0 strips; shuffle phase covers latency
        if (it < 3) {
            urb += 800; uib += 800;
            u0 = LDU2(uoff); u1 = LDU2(uoff+8); u2 = LDU2(uoff+16); u3 = LDU2(uoff+24);
        }

        // reduce over the 8 k-blocks (lane bits 3..5)
        float p[8] = {p10.x, p10.y, p11.x, p11.y, p20.x, p20.y, p21.x, p21.y};
        #pragma unroll
        for (int q = 0; q < 8; ++q) {
            p[q] += __shfl_xor(p[q], 8);
            p[q] += __shfl_xor(p[q], 32);
        }
        float4 ph;
        {
            float k0r = nn ? p[2] : p[0], s0r = nn ? p[0] : p[2];
            float k0i = nn ? p[3] : p[1], s0i = nn ? p[1] : p[3];
            float k1r = nn ? p[6] : p[4], s1r = nn ? p[4] : p[6];
            float k1i = nn ? p[7] : p[5], s1i = nn ? p[5] : p[7];
            ph.x = k0r + __shfl_xor(s0r, 16);
            ph.y = k0i + __shfl_xor(s0i, 16);
            ph.z = k1r + __shfl_xor(s1r, 16);
            ph.w = k1i + __shfl_xor(s1i, 16);
        }

        // ---- F norms ----  (F raw at W[200..263])
        float s1, s2;
        {
            int idx = lane & 15;
            int sel = (lane >> 4) & 1;
            float fr = W[200 + sel*32 + idx];
            float fi = W[216 + sel*32 + idx];
            float m = fr*fr + fi*fi;
            #pragma unroll
            for (int s = 1; s < 16; s <<= 1) m += __shfl_xor(m, s);
            float other = __shfl_xor(m, 16);
            float nrm1 = sel ? other : m;
            float nrm2 = sel ? m : other;
            s1 = sqrtf(2.0f / nrm1);
            s2 = sqrtf(2.0f / nrm2);
        }

        // ---- A/C entries: ent[it][0..7] = {A,C} for R1; [8..15] for R2 ----
        {
            int jf = t*2 + rr;
            float2 f1 = make_float2(W[200 + jf], W[216 + jf]);
            float2 f2 = make_float2(W[232 + jf], W[248 + jf]);
            float2 phi1n = make_float2(ph.x, ph.y);
            float2 phi2n = make_float2(ph.z, ph.w);
            bool lo = (e8 < 4);
            float2 E0 = cmul(phi1n, lo ? f1 : f2);
            float2 E1 = cmul(phi2n, lo ? f2 : f1);
            #pragma unroll
            for (int s = 1; s < 8; s <<= 1) {
                E0.x += __shfl_xor(E0.x, s); E0.y += __shfl_xor(E0.y, s);
                E1.x += __shfl_xor(E1.x, s); E1.y += __shfl_xor(E1.y, s);
            }
            if (t == 0) {
                ent[wave][it][e8]     = cscale(lo ? s1 : s2, E0);
                ent[wave][it][e8 + 8] = cscale(lo ? s2 : s1, E1);
            }
        }
    }
    #undef STAGE
    #undef LDU2
    #undef JGROUP_PK
    asm volatile("s_waitcnt lgkmcnt(0)" ::: "memory");
    __builtin_amdgcn_wave_barrier();

    // ---- batched 2x2 complex rate: lanes 0..7 -> (it = lane>>1, R1/R2 = lane&1) ----
    float negR = 0.0f;
    if (lane < 8) {
        const float2* e = &ent[wave][lane >> 1][(lane & 1) * 8];
        float2 A00=e[0], A01=e[1], A10=e[2], A11=e[3];
        float2 C00=e[4], C01=e[5], C10=e[6], C11=e[7];
        float mu00 = C00.x*C00.x + C00.y*C00.y + C01.x*C01.x + C01.y*C01.y + NOISE;
        float mu11 = C10.x*C10.x + C10.y*C10.y + C11.x*C11.x + C11.y*C11.y + NOISE;
        float2 mu01 = cadd(cmulconj(C00, C10), cmulconj(C01, C11));
        mu01.x += NOISE;
        float det = mu00*mu11 - (mu01.x*mu01.x + mu01.y*mu01.y);
        float inv = 1.0f / det;
        float2 mu01c = make_float2(mu01.x, -mu01.y);
        float2 X00 = cscale(inv, csub(cscale(mu11, A00), cmul(mu01,  A10)));
        float2 X01 = cscale(inv, csub(cscale(mu11, A01), cmul(mu01,  A11)));
        float2 X10 = cscale(inv, csub(cscale(mu00, A10), cmul(mu01c, A00)));
        float2 X11 = cscale(inv, csub(cscale(mu00, A11), cmul(mu01c, A01)));
        float2 I00 = cadd(cconjmul(A00, X00), cconjmul(A10, X10));
        float2 I01 = cadd(cconjmul(A00, X01), cconjmul(A10, X11));
        float2 I10 = cadd(cconjmul(A01, X00), cconjmul(A11, X10));
        float2 I11 = cadd(cconjmul(A01, X01), cconjmul(A11, X11));
        I00.x += 1.0f; I01.x += 1.0f; I10.x += 1.0f; I11.x += 1.0f;
        float2 dT = csub(cmul(I00, I11), cmul(I01, I10));
        negR = -0.5f * logf(dT.x*dT.x + dT.y*dT.y);  // -Re(log z) = -ln|z|
    }
    // pairwise max over (R1,R2), then sum the 4 batch elements
    float m = fmaxf(negR, __shfl_xor(negR, 1));
    m += __shfl_xor(m, 2);
    m += __shfl_xor(m, 4);
    if (lane == 0) wsum[wave] = m;

    __syncthreads();
    if (threadIdx.x == 0)
        partial[blockIdx.x] = (wsum[0] + wsum[1]) + (wsum[2] + wsum[3]);
}

__global__ __launch_bounds__(256) void reduce_kernel(
    const float* __restrict__ partial, int n, float invB, float* __restrict__ out)
{
    __shared__ float sd[256];
    float s = 0.0f;
    for (int i = threadIdx.x; i < n; i += 256) s += partial[i];
    sd[threadIdx.x] = s;
    __syncthreads();
    for (int o = 128; o > 0; o >>= 1) {
        if ((int)threadIdx.x < o) sd[threadIdx.x] += sd[threadIdx.x + o];
        __syncthreads();
    }
    if (threadIdx.x == 0) out[0] = sd[0] * invB;
}

extern "C" void kernel_launch(void* const* d_in, const int* in_sizes, int n_in,
                              void* d_out, int out_size, void* d_ws, size_t ws_size,
                              hipStream_t stream) {
    const float* t1  = (const float*)d_in[0];
    const float* G1r = (const float*)d_in[1];
    const float* G1i = (const float*)d_in[2];
    const float* G2r = (const float*)d_in[3];
    const float* G2i = (const float*)d_in[4];
    const float* Ur  = (const float*)d_in[5];
    const float* Ui  = (const float*)d_in[6];

    const int B = in_sizes[0] / 264;        // 65536
    const int nblocks = B / 16;             // 16 batch elements per block
    float* partial = (float*)d_ws;          // nblocks floats

    rate_kernel<<<nblocks, 256, 0, stream>>>(t1, G1r, G1i, G2r, G2i, Ur, Ui, partial);
    reduce_kernel<<<1, 256, 0, stream>>>(partial, nblocks, 1.0f / (float)B, (float*)d_out);
}